// Round 6
// baseline (494.906 us; speedup 1.0000x reference)
//
#include <hip/hip_runtime.h>
#include <hip/hip_bf16.h>
#include <math.h>

#define B_    2
#define S_    2048
#define D_    1024
#define H_    16
#define DH_   64
#define HALF_ 32
#define M_    (B_ * S_)   // 4096 rows

typedef __attribute__((ext_vector_type(8))) short bf16x8;
typedef __attribute__((ext_vector_type(4))) float f32x4;

#define MFMA(a, b, c) __builtin_amdgcn_mfma_f32_16x16x32_bf16((a), (b), (c), 0, 0, 0)

#if defined(__has_builtin)
#if __has_builtin(__builtin_amdgcn_global_load_lds)
#define HAVE_GLOAD_LDS 1
#endif
#endif

#ifdef HAVE_GLOAD_LDS
// Direct global->LDS 16B DMA. LDS dest must be wave-uniform base (+lane*16
// implicit); global src is per-lane (pre-swizzled to match swizzled layout).
#define GLOAD16(gp, lp)                                                        \
  __builtin_amdgcn_global_load_lds(                                            \
      (const __attribute__((address_space(1))) void*)(gp),                     \
      (__attribute__((address_space(3))) void*)(lp), 16, 0, 0)
#endif

__device__ __forceinline__ ushort f2bf(float f) {   // RNE fp32->bf16
  uint u = __float_as_uint(f);
  u += 0x7fffu + ((u >> 16) & 1u);
  return (ushort)(u >> 16);
}
__device__ __forceinline__ float bf2f(ushort h) {
  return __uint_as_float(((uint)h) << 16);
}
__device__ __forceinline__ void split4(float4 v, uint2* hi, uint2* lo) {
  ushort h0 = f2bf(v.x), h1 = f2bf(v.y), h2 = f2bf(v.z), h3 = f2bf(v.w);
  hi->x = (uint)h0 | ((uint)h1 << 16);
  hi->y = (uint)h2 | ((uint)h3 << 16);
  ushort e0 = f2bf(v.x - bf2f(h0)), e1 = f2bf(v.y - bf2f(h1));
  ushort e2 = f2bf(v.z - bf2f(h2)), e3 = f2bf(v.w - bf2f(h3));
  lo->x = (uint)e0 | ((uint)e1 << 16);
  lo->y = (uint)e2 | ((uint)e3 << 16);
}

// ---------------------------------------------------------------------------
// fp32 -> bf16 hi/lo plane split.
// ---------------------------------------------------------------------------
__global__ void split_x_kernel(const float4* __restrict__ src,
                               uint2* __restrict__ hi, uint2* __restrict__ lo,
                               int n4) {
  int i = blockIdx.x * blockDim.x + threadIdx.x;
  if (i >= n4) return;
  uint2 h, l;
  split4(src[i], &h, &l);
  hi[i] = h;
  lo[i] = l;
}

__global__ void split_w_kernel(const float4* __restrict__ w0,
                               const float4* __restrict__ w1,
                               const float4* __restrict__ w2,
                               const float4* __restrict__ w3,
                               uint2* __restrict__ h0, uint2* __restrict__ l0,
                               uint2* __restrict__ h1, uint2* __restrict__ l1,
                               uint2* __restrict__ h2, uint2* __restrict__ l2,
                               uint2* __restrict__ h3, uint2* __restrict__ l3,
                               int n4) {
  int i = blockIdx.x * blockDim.x + threadIdx.x;
  if (i >= n4) return;
  int y = blockIdx.y;
  const float4* src = (y == 0) ? w0 : (y == 1) ? w1 : (y == 2) ? w2 : w3;
  uint2* hi = (y == 0) ? h0 : (y == 1) ? h1 : (y == 2) ? h2 : h3;
  uint2* lo = (y == 0) ? l0 : (y == 1) ? l1 : (y == 2) ? l2 : l3;
  uint2 h, l;
  split4(src[i], &h, &l);
  hi[i] = h;
  lo[i] = l;
}

// ---------------------------------------------------------------------------
// RoPE cos/sin table: tab[s*32+f] = {cos, sin}(s * 10000^(-f/32))
// ---------------------------------------------------------------------------
__global__ void rope_tab_kernel(float2* __restrict__ tab) {
  int idx = blockIdx.x * blockDim.x + threadIdx.x;
  if (idx >= S_ * HALF_) return;
  int s = idx >> 5;
  int f = idx & (HALF_ - 1);
  float invf = powf(10000.0f, -((float)f) / (float)HALF_);
  float ang = (float)s * invf;
  tab[idx] = make_float2(cosf(ang), sinf(ang));
}

// ---------------------------------------------------------------------------
// Shared GEMM staging: 4 LDS buffers [128 rows][32 cols] bf16, stored LDS-
// linear; logical 16B slot s' holds global chunk s'^(row&3) (bank-spread).
// With global_load_lds: linear LDS dest + pre-swizzled per-lane global src.
// Fallback: reg-staged uint4 loads + swizzled ds_write (identical layout).
// ---------------------------------------------------------------------------
#ifdef HAVE_GLOAD_LDS
#define STAGE_TILES(Asrc_h, Asrc_l, Bsrc_h, Bsrc_l, rowA0, rowB0, kt)          \
  do {                                                                         \
    _Pragma("unroll") for (int p = 0; p < 2; ++p) {                            \
      int cch = wv * 2 + p;             /* chunk 0..7, wave-uniform */         \
      int lrow = cch * 16 + (l >> 2);   /* row 0..127 (per-lane) */            \
      int sl = (l & 3) ^ (lrow & 3);    /* pre-swizzled 16B slot */            \
      size_t ga = (size_t)((rowA0) + lrow) * D_ + (kt) + sl * 8;               \
      size_t gb = (size_t)((rowB0) + lrow) * D_ + (kt) + sl * 8;               \
      GLOAD16((Asrc_h) + ga, (char*)Ah + cch * 1024);                          \
      GLOAD16((Asrc_l) + ga, (char*)Al + cch * 1024);                          \
      GLOAD16((Bsrc_h) + gb, (char*)Bh + cch * 1024);                          \
      GLOAD16((Bsrc_l) + gb, (char*)Bl + cch * 1024);                          \
    }                                                                          \
  } while (0)
#else
#define STAGE_TILES(Asrc_h, Asrc_l, Bsrc_h, Bsrc_l, rowA0, rowB0, kt)          \
  do {                                                                         \
    _Pragma("unroll") for (int p = 0; p < 2; ++p) {                            \
      int idx = t + p * 256;                                                   \
      int row = idx >> 2;                                                      \
      int ch = idx & 3;                                                        \
      int off = (row << 5) + ((ch ^ (row & 3)) << 3);                          \
      size_t ga = (size_t)((rowA0) + row) * D_ + (kt) + ch * 8;                \
      size_t gb = (size_t)((rowB0) + row) * D_ + (kt) + ch * 8;                \
      *(uint4*)&Ah[off] = *(const uint4*)&(Asrc_h)[ga];                        \
      *(uint4*)&Al[off] = *(const uint4*)&(Asrc_l)[ga];                        \
      *(uint4*)&Bh[off] = *(const uint4*)&(Bsrc_h)[gb];                        \
      *(uint4*)&Bl[off] = *(const uint4*)&(Bsrc_l)[gb];                        \
    }                                                                          \
  } while (0)
#endif

// ---------------------------------------------------------------------------
// QKV projection from pre-split planes.  y = x W^T.
// 128x128 tile, BK=32, 4 waves each 64x64 (4x4 frags of 16x16x32, 3-term).
// XCD-aware block swizzle (256 blocks/z-slice, %8==0 -> simple form).
// Epilogue: RoPE (Q,K) -> hi/lo [bh][s][dh];  V -> hi/lo transposed
// [bh][dh][s] with packed ushort4 stores.
// ---------------------------------------------------------------------------
__global__ __launch_bounds__(256) void qkv_mfma_kernel(
    const ushort* __restrict__ xh, const ushort* __restrict__ xl,
    const ushort* __restrict__ Wqh, const ushort* __restrict__ Wql,
    const ushort* __restrict__ Wkh, const ushort* __restrict__ Wkl,
    const ushort* __restrict__ Wvh, const ushort* __restrict__ Wvl,
    ushort* __restrict__ Qh, ushort* __restrict__ Ql,
    ushort* __restrict__ Kh, ushort* __restrict__ Kl,
    ushort* __restrict__ Vth, ushort* __restrict__ Vtl,
    const float2* __restrict__ tab) {
  __shared__ __align__(16) ushort Ah[128 * 32], Al[128 * 32];
  __shared__ __align__(16) ushort Bh[128 * 32], Bl[128 * 32];

  const int which = blockIdx.z;
  const ushort* __restrict__ Wh = (which == 0) ? Wqh : (which == 1) ? Wkh : Wvh;
  const ushort* __restrict__ Wl = (which == 0) ? Wql : (which == 1) ? Wkl : Wvl;

  // XCD swizzle: 256 blocks per z-slice, 32 per XCD chunk.
  const int lin = (int)blockIdx.y * 8 + (int)blockIdx.x;
  const int wid = (lin & 7) * 32 + (lin >> 3);
  const int r0 = (wid >> 3) * 128;
  const int c0 = (wid & 7) * 128;

  const int t = threadIdx.x;
  const int l = t & 63, wv = t >> 6;
  const int g = l >> 4, li = l & 15;
  const int wr = (wv >> 1) * 64, wc = (wv & 1) * 64;

  f32x4 zero4 = {0.f, 0.f, 0.f, 0.f};
  f32x4 acc[4][4];
#pragma unroll
  for (int i = 0; i < 4; ++i)
#pragma unroll
    for (int j = 0; j < 4; ++j) acc[i][j] = zero4;

  for (int kt = 0; kt < D_; kt += 32) {
    __syncthreads();
    STAGE_TILES(xh, xl, Wh, Wl, r0, c0, kt);
    __syncthreads();   // compiler drains vmcnt(0)/lgkmcnt(0) here

    bf16x8 ah[4], al[4], bh[4], bl[4];
#pragma unroll
    for (int fm = 0; fm < 4; ++fm) {
      int row = wr + fm * 16 + li;
      int idx = (row << 5) + ((g ^ (row & 3)) << 3);
      ah[fm] = *(const bf16x8*)&Ah[idx];
      al[fm] = *(const bf16x8*)&Al[idx];
    }
#pragma unroll
    for (int fn = 0; fn < 4; ++fn) {
      int row = wc + fn * 16 + li;
      int idx = (row << 5) + ((g ^ (row & 3)) << 3);
      bh[fn] = *(const bf16x8*)&Bh[idx];
      bl[fn] = *(const bf16x8*)&Bl[idx];
    }
    __builtin_amdgcn_s_setprio(1);
#pragma unroll
    for (int fm = 0; fm < 4; ++fm)
#pragma unroll
      for (int fn = 0; fn < 4; ++fn) {
        acc[fm][fn] = MFMA(ah[fm], bh[fn], acc[fm][fn]);
        acc[fm][fn] = MFMA(ah[fm], bl[fn], acc[fm][fn]);
        acc[fm][fn] = MFMA(al[fm], bh[fn], acc[fm][fn]);
      }
    __builtin_amdgcn_s_setprio(0);
  }

  // Epilogue.  C layout: col = li, row = 4*g + reg (per 16x16 frag).
  if (which < 2) {
#pragma unroll
    for (int fm = 0; fm < 4; ++fm) {
#pragma unroll
      for (int reg = 0; reg < 4; ++reg) {
        int r = r0 + wr + fm * 16 + g * 4 + reg;
        int b = r >> 11, s = r & (S_ - 1);
#pragma unroll
        for (int fn = 0; fn < 4; ++fn) {
          float v = acc[fm][fn][reg];
          int c = c0 + wc + fn * 16 + li;
          int h = c >> 6, dc = c & 63;
          float pr = __shfl_xor(v, 1);   // partner col c^1, same row
          int f = dc >> 1;
          float2 cssn = tab[(s << 5) + f];
          float res = (c & 1) ? (pr * cssn.y + v * cssn.x)
                              : (v * cssn.x - pr * cssn.y);
          size_t o = ((size_t)((b << 4) + h) * S_ + s) * DH_ + dc;
          ushort hi = f2bf(res);
          ushort lo = f2bf(res - bf2f(hi));
          if (which == 0) { Qh[o] = hi; Ql[o] = lo; }
          else            { Kh[o] = hi; Kl[o] = lo; }
        }
      }
    }
  } else {
    // V: transposed planes [bh][dh][s]; pack 4 consecutive s per store.
#pragma unroll
    for (int fm = 0; fm < 4; ++fm) {
      int rbase = r0 + wr + fm * 16 + g * 4;   // multiple of 4
      int b = rbase >> 11, s0 = rbase & (S_ - 1);
#pragma unroll
      for (int fn = 0; fn < 4; ++fn) {
        int c = c0 + wc + fn * 16 + li;
        int h = c >> 6, dc = c & 63;
        ushort hv[4], lv[4];
#pragma unroll
        for (int reg = 0; reg < 4; ++reg) {
          float v = acc[fm][fn][reg];
          hv[reg] = f2bf(v);
          lv[reg] = f2bf(v - bf2f(hv[reg]));
        }
        size_t o = ((size_t)((b << 4) + h) * DH_ + dc) * S_ + s0;
        *(ushort4*)&Vth[o] = make_ushort4(hv[0], hv[1], hv[2], hv[3]);
        *(ushort4*)&Vtl[o] = make_ushort4(lv[0], lv[1], lv[2], lv[3]);
      }
    }
  }
}

// ---------------------------------------------------------------------------
// Flash causal attention, split-MFMA.  Block = 4 independent waves, each
// owning 32 q-rows (128/block); kv-tile 64.  No block barriers.
// K from [bh][s][dh] planes, V from [bh][dh][s] planes (L2-resident; the
// XCD swizzle gives each XCD 4 consecutive heads' K/V ~= 4 MB ~= its L2).
// P kept per-wave in LDS ([32][64] hi/lo, XOR-swizzled).  Output written
// as bf16 hi/lo planes [b][s][d] for the out-projection.
// ---------------------------------------------------------------------------
__global__ __launch_bounds__(256) void attn_mfma_kernel(
    const ushort* __restrict__ Qh, const ushort* __restrict__ Ql,
    const ushort* __restrict__ Kh, const ushort* __restrict__ Kl,
    const ushort* __restrict__ Vth, const ushort* __restrict__ Vtl,
    ushort* __restrict__ aoh, ushort* __restrict__ aol) {
  __shared__ __align__(16) ushort Ps[4][2][32 * 64];

  // XCD swizzle over 512 blocks, 64 per XCD chunk; heavy qi first per chunk.
  const int lin = (int)blockIdx.y * 16 + (int)blockIdx.x;
  const int wid = (lin & 7) * 64 + (lin >> 3);
  const int bh = wid >> 4;
  const int qi = 15 - (wid & 15);

  const int t = threadIdx.x, w = t >> 6, l = t & 63;
  const int g = l >> 4, li = l & 15;
  const int R0 = qi * 128 + w * 32;

  const size_t qkBase = (size_t)bh * S_ * DH_;
  const size_t vBase  = (size_t)bh * DH_ * S_;

  // Q fragments: [fm][kc], rows R0 + fm*16 + li
  bf16x8 qh[2][2], ql[2][2];
#pragma unroll
  for (int fm = 0; fm < 2; ++fm)
#pragma unroll
    for (int kc = 0; kc < 2; ++kc) {
      size_t off = qkBase + (size_t)(R0 + fm * 16 + li) * DH_ + kc * 32 + g * 8;
      qh[fm][kc] = *(const bf16x8*)&Qh[off];
      ql[fm][kc] = *(const bf16x8*)&Ql[off];
    }

  f32x4 zero4 = {0.f, 0.f, 0.f, 0.f};
  float m[2][4], ls[2][4];
  f32x4 o[2][4];
#pragma unroll
  for (int fm = 0; fm < 2; ++fm) {
#pragma unroll
    for (int r = 0; r < 4; ++r) { m[fm][r] = -INFINITY; ls[fm][r] = 0.f; }
#pragma unroll
    for (int fd = 0; fd < 4; ++fd) o[fm][fd] = zero4;
  }

  const int nT = 2 * qi + 1 + (w >> 1);   // per-wave causal tile count

  for (int t2 = 0; t2 < nT; ++t2) {
    const int kv0 = t2 * 64;
    const bool diag = (t2 == nT - 1);

    // ---- S = Q K^T  (32 x 64 per wave), 3-term split ----
    f32x4 sc[2][4];
#pragma unroll
    for (int fm = 0; fm < 2; ++fm)
#pragma unroll
      for (int fn = 0; fn < 4; ++fn) sc[fm][fn] = zero4;

#pragma unroll
    for (int fn = 0; fn < 4; ++fn) {
#pragma unroll
      for (int kc = 0; kc < 2; ++kc) {
        size_t off =
            qkBase + (size_t)(kv0 + fn * 16 + li) * DH_ + kc * 32 + g * 8;
        bf16x8 kh = *(const bf16x8*)&Kh[off];
        bf16x8 kl = *(const bf16x8*)&Kl[off];
        __builtin_amdgcn_s_setprio(1);
#pragma unroll
        for (int fm = 0; fm < 2; ++fm) {
          sc[fm][fn] = MFMA(qh[fm][kc], kh, sc[fm][fn]);
          sc[fm][fn] = MFMA(qh[fm][kc], kl, sc[fm][fn]);
          sc[fm][fn] = MFMA(ql[fm][kc], kh, sc[fm][fn]);
        }
        __builtin_amdgcn_s_setprio(0);
      }
    }

    // ---- scale + causal mask (diagonal tile only) ----
#pragma unroll
    for (int fm = 0; fm < 2; ++fm)
#pragma unroll
      for (int fn = 0; fn < 4; ++fn)
#pragma unroll
        for (int r = 0; r < 4; ++r) {
          float s = sc[fm][fn][r] * 0.125f;
          if (diag) {
            int colg = kv0 + fn * 16 + li;
            int rowg = R0 + fm * 16 + g * 4 + r;
            if (colg > rowg) s = -1e30f;
          }
          sc[fm][fn][r] = s;
        }

    // ---- online softmax per row; P -> wave-private LDS ----
#pragma unroll
    for (int fm = 0; fm < 2; ++fm) {
#pragma unroll
      for (int r = 0; r < 4; ++r) {
        float ml = fmaxf(fmaxf(sc[fm][0][r], sc[fm][1][r]),
                         fmaxf(sc[fm][2][r], sc[fm][3][r]));
        ml = fmaxf(ml, __shfl_xor(ml, 1));
        ml = fmaxf(ml, __shfl_xor(ml, 2));
        ml = fmaxf(ml, __shfl_xor(ml, 4));
        ml = fmaxf(ml, __shfl_xor(ml, 8));
        float mn = fmaxf(m[fm][r], ml);
        float al = __expf(m[fm][r] - mn);
        m[fm][r] = mn;
        float p[4];
        float rs = 0.f;
#pragma unroll
        for (int fn = 0; fn < 4; ++fn) {
          p[fn] = __expf(sc[fm][fn][r] - mn);
          rs += p[fn];
        }
        rs += __shfl_xor(rs, 1);
        rs += __shfl_xor(rs, 2);
        rs += __shfl_xor(rs, 4);
        rs += __shfl_xor(rs, 8);
        ls[fm][r] = ls[fm][r] * al + rs;
#pragma unroll
        for (int fd = 0; fd < 4; ++fd) o[fm][fd][r] *= al;

        int prow = fm * 16 + g * 4 + r;   // 0..31
#pragma unroll
        for (int fn = 0; fn < 4; ++fn) {
          int idx = ((prow << 6) + fn * 16 + li) ^ ((prow & 7) << 3);
          ushort hi = f2bf(p[fn]);
          Ps[w][0][idx] = hi;
          Ps[w][1][idx] = f2bf(p[fn] - bf2f(hi));
        }
      }
    }
    __builtin_amdgcn_wave_barrier();   // same-wave DS pipe is in-order

    // ---- O += P V ----
#pragma unroll
    for (int kc = 0; kc < 2; ++kc) {
      bf16x8 pah[2], pal[2];
#pragma unroll
      for (int fm = 0; fm < 2; ++fm) {
        int ridx = fm * 16 + li;
        int idx = (ridx << 6) + ((kc * 32 + g * 8) ^ ((ridx & 7) << 3));
        pah[fm] = *(const bf16x8*)&Ps[w][0][idx];
        pal[fm] = *(const bf16x8*)&Ps[w][1][idx];
      }
#pragma unroll
      for (int fd = 0; fd < 4; ++fd) {
        size_t off =
            vBase + (size_t)(fd * 16 + li) * S_ + kv0 + kc * 32 + g * 8;
        bf16x8 vh = *(const bf16x8*)&Vth[off];
        bf16x8 vl = *(const bf16x8*)&Vtl[off];
        __builtin_amdgcn_s_setprio(1);
#pragma unroll
        for (int fm = 0; fm < 2; ++fm) {
          o[fm][fd] = MFMA(pah[fm], vh, o[fm][fd]);
          o[fm][fd] = MFMA(pah[fm], vl, o[fm][fd]);
          o[fm][fd] = MFMA(pal[fm], vh, o[fm][fd]);
        }
        __builtin_amdgcn_s_setprio(0);
      }
    }
    __builtin_amdgcn_wave_barrier();
  }

  // ---- normalize + write attn-out as bf16 hi/lo planes [b][s][d] ----
  const int b = bh >> 4, h = bh & 15;
#pragma unroll
  for (int fm = 0; fm < 2; ++fm)
#pragma unroll
    for (int fd = 0; fd < 4; ++fd)
#pragma unroll
      for (int r = 0; r < 4; ++r) {
        int srow = R0 + fm * 16 + g * 4 + r;
        int c = h * DH_ + fd * 16 + li;
        float v = o[fm][fd][r] / ls[fm][r];
        size_t oo = ((size_t)b * S_ + srow) * D_ + c;
        ushort hi = f2bf(v);
        aoh[oo] = hi;
        aol[oo] = f2bf(v - bf2f(hi));
      }
}

// ---------------------------------------------------------------------------
// Output projection from planes: out = ao Wo^T, fp32 out.
// ---------------------------------------------------------------------------
__global__ __launch_bounds__(256) void out_mfma_kernel(
    const ushort* __restrict__ Aph, const ushort* __restrict__ Apl,
    const ushort* __restrict__ Wh, const ushort* __restrict__ Wl,
    float* __restrict__ out) {
  __shared__ __align__(16) ushort Ah[128 * 32], Al[128 * 32];
  __shared__ __align__(16) ushort Bh[128 * 32], Bl[128 * 32];

  // XCD swizzle: 256 blocks, 32 per XCD chunk.
  const int lin = (int)blockIdx.y * 8 + (int)blockIdx.x;
  const int wid = (lin & 7) * 32 + (lin >> 3);
  const int r0 = (wid >> 3) * 128;
  const int c0 = (wid & 7) * 128;

  const int t = threadIdx.x;
  const int l = t & 63, wv = t >> 6;
  const int g = l >> 4, li = l & 15;
  const int wr = (wv >> 1) * 64, wc = (wv & 1) * 64;

  f32x4 zero4 = {0.f, 0.f, 0.f, 0.f};
  f32x4 acc[4][4];
#pragma unroll
  for (int i = 0; i < 4; ++i)
#pragma unroll
    for (int j = 0; j < 4; ++j) acc[i][j] = zero4;

  for (int kt = 0; kt < D_; kt += 32) {
    __syncthreads();
    STAGE_TILES(Aph, Apl, Wh, Wl, r0, c0, kt);
    __syncthreads();

    bf16x8 ah[4], al[4], bh[4], bl[4];
#pragma unroll
    for (int fm = 0; fm < 4; ++fm) {
      int row = wr + fm * 16 + li;
      int idx = (row << 5) + ((g ^ (row & 3)) << 3);
      ah[fm] = *(const bf16x8*)&Ah[idx];
      al[fm] = *(const bf16x8*)&Al[idx];
    }
#pragma unroll
    for (int fn = 0; fn < 4; ++fn) {
      int row = wc + fn * 16 + li;
      int idx = (row << 5) + ((g ^ (row & 3)) << 3);
      bh[fn] = *(const bf16x8*)&Bh[idx];
      bl[fn] = *(const bf16x8*)&Bl[idx];
    }
    __builtin_amdgcn_s_setprio(1);
#pragma unroll
    for (int fm = 0; fm < 4; ++fm)
#pragma unroll
      for (int fn = 0; fn < 4; ++fn) {
        acc[fm][fn] = MFMA(ah[fm], bh[fn], acc[fm][fn]);
        acc[fm][fn] = MFMA(ah[fm], bl[fn], acc[fm][fn]);
        acc[fm][fn] = MFMA(al[fm], bh[fn], acc[fm][fn]);
      }
    __builtin_amdgcn_s_setprio(0);
  }

#pragma unroll
  for (int fm = 0; fm < 4; ++fm)
#pragma unroll
    for (int reg = 0; reg < 4; ++reg) {
      int r = r0 + wr + fm * 16 + g * 4 + reg;
#pragma unroll
      for (int fn = 0; fn < 4; ++fn) {
        int c = c0 + wc + fn * 16 + li;
        out[(size_t)r * D_ + c] = acc[fm][fn][reg];
      }
    }
}

// ---------------------------------------------------------------------------
extern "C" void kernel_launch(void* const* d_in, const int* in_sizes, int n_in,
                              void* d_out, int out_size, void* d_ws,
                              size_t ws_size, hipStream_t stream) {
  (void)in_sizes; (void)n_in; (void)out_size; (void)ws_size;
  const float* x  = (const float*)d_in[0];
  const float* Wq = (const float*)d_in[1];
  const float* Wk = (const float*)d_in[2];
  const float* Wv = (const float*)d_in[3];
  const float* Wo = (const float*)d_in[4];
  float* out = (float*)d_out;

  // ws layout (80.5 MB peak):
  //   [0,48M)      : Q/K/V hi-lo planes (6 x 8 MB)
  //   [48M,48.5M)  : rope table
  //   [48.5M,64.5M): Wq/Wk/Wv/Wo hi-lo planes (8 x 2 MB)
  //   [64.5M,80.5M): x hi/lo planes; reused as ao hi/lo planes after qkv
  const size_t NP = (size_t)B_ * H_ * S_ * DH_;   // 4,194,304 elems / plane
  const size_t NW = (size_t)D_ * D_;              // 1,048,576 elems / plane
  char* w = (char*)d_ws;
  ushort* Qh  = (ushort*)w;
  ushort* Ql  = Qh + NP;
  ushort* Kh  = Ql + NP;
  ushort* Kl  = Kh + NP;
  ushort* Vth = Kl + NP;
  ushort* Vtl = Vth + NP;
  float2* tab = (float2*)(w + 6 * NP * sizeof(ushort));
  ushort* Wqh = (ushort*)(w + 6 * NP * sizeof(ushort) +
                          (size_t)S_ * HALF_ * sizeof(float2));
  ushort* Wql = Wqh + NW;
  ushort* Wkh = Wql + NW;
  ushort* Wkl = Wkh + NW;
  ushort* Wvh = Wkl + NW;
  ushort* Wvl = Wvh + NW;
  ushort* Woh = Wvl + NW;
  ushort* Wol = Woh + NW;
  ushort* xh  = Wol + NW;                  // 8 MB
  ushort* xl  = xh + (size_t)M_ * D_;      // 8 MB
  ushort* aoh = xh;                        // reuse after qkv done
  ushort* aol = xl;

  rope_tab_kernel<<<(S_ * HALF_ + 255) / 256, 256, 0, stream>>>(tab);

  const int n4x = M_ * D_ / 4;    // 1,048,576
  const int n4w = D_ * D_ / 4;    //   262,144
  split_x_kernel<<<(n4x + 255) / 256, 256, 0, stream>>>(
      (const float4*)x, (uint2*)xh, (uint2*)xl, n4x);
  split_w_kernel<<<dim3((n4w + 255) / 256, 4), 256, 0, stream>>>(
      (const float4*)Wq, (const float4*)Wk, (const float4*)Wv,
      (const float4*)Wo,
      (uint2*)Wqh, (uint2*)Wql, (uint2*)Wkh, (uint2*)Wkl,
      (uint2*)Wvh, (uint2*)Wvl, (uint2*)Woh, (uint2*)Wol, n4w);

  qkv_mfma_kernel<<<dim3(8, 32, 3), 256, 0, stream>>>(
      xh, xl, Wqh, Wql, Wkh, Wkl, Wvh, Wvl,
      Qh, Ql, Kh, Kl, Vth, Vtl, tab);

  attn_mfma_kernel<<<dim3(16, 32), 256, 0, stream>>>(
      Qh, Ql, Kh, Kl, Vth, Vtl, aoh, aol);

  out_mfma_kernel<<<dim3(8, 32), 256, 0, stream>>>(
      aoh, aol, Woh, Wol, out);
}